// Round 3
// baseline (545.180 us; speedup 1.0000x reference)
//
#include <hip/hip_runtime.h>
#include <hip/hip_bf16.h>
#include <stdint.h>

// GraphConv: out = normalize((adj@x + x)@W + bias, dim=f)
// R6: k0 stage rebuilt for efficiency; k1 byte-identical to R5 (attribution).
//   K0w: wt[o][f] = w[f][o]  bf16, one tiny block (removes 512x redundant
//        per-block scalar transpose).
//   K0 : ut[b][o][m] = (x@W)^T   (mini-k1: 512 thr, BK=64 x 2 steps,
//        A=x fp32->bf16 regs + swizzled ds_write, B=wt via global_load_lds
//        with pre-swizzled source, acc[2][4], bf16x4 direct stores)
//   K1 : v = adj@u; epilogue z = v + u + bias, out = z/max(||z||,eps).

typedef __bf16 bf16;
typedef __bf16 bf16x4 __attribute__((ext_vector_type(4)));
typedef __bf16 bf16x8 __attribute__((ext_vector_type(8)));
typedef float floatx4 __attribute__((ext_vector_type(4)));

#define B_ 8
#define N_ 8192
#define F_ 128

__device__ __forceinline__ void async_copy16(const void* g, void* l) {
  __builtin_amdgcn_global_load_lds(
      (const __attribute__((address_space(1))) uint32_t*)g,
      (__attribute__((address_space(3))) uint32_t*)l, 16, 0, 0);
}

// ---------------- K0w: wt[o][f] = (bf16)w[f][o] ----------------------------
__global__ __launch_bounds__(256) void k0w(const float* __restrict__ w,
                                           bf16* __restrict__ wt) {
  __shared__ bf16 T[128][129];
  const int tid = threadIdx.x;
#pragma unroll
  for (int c = 0; c < 16; ++c) {
    int lin = (c << 8) + tid;       // 0..4095
    int f = lin >> 5;               // 0..127
    int g = lin & 31;               // float4 group along o
    float4 v = *(const float4*)(w + (size_t)f * F_ + (g << 2));
    T[f][(g << 2) + 0] = (bf16)v.x;
    T[f][(g << 2) + 1] = (bf16)v.y;
    T[f][(g << 2) + 2] = (bf16)v.z;
    T[f][(g << 2) + 3] = (bf16)v.w;
  }
  __syncthreads();
#pragma unroll
  for (int c = 0; c < 16; ++c) {
    int lin = (c << 8) + tid;
    int o = lin >> 5;
    int g = lin & 31;               // 4-f group
    bf16x4 pk;
#pragma unroll
    for (int q = 0; q < 4; ++q) pk[q] = T[(g << 2) + q][o];
    *(bf16x4*)(wt + (size_t)o * F_ + (g << 2)) = pk;
  }
}

// ---------------- K0: ut[b][o][m] = (x[b]@W)^T  (fp32 in, bf16 out) --------
// Mini-k1: 128 m-rows x 128 o-cols per block, 512 threads (8 waves, 4x2),
// BK=64, 2 K-steps. Same swizzle/fragment machinery as k1.
__global__ __launch_bounds__(512, 4) void k0_xw_t(const float* __restrict__ x,
                                                  const bf16* __restrict__ wt,
                                                  bf16* __restrict__ ut) {
  __shared__ bf16 As[128][64];   // x tile, bf16, chunk-swizzled
  __shared__ bf16 Bs[128][64];   // wt tile, bf16, chunk-swizzled
  const int tid = threadIdx.x;            // 0..511
  const int lane = tid & 63;
  const int wv = tid >> 6;                // 0..7
  const int wr = wv >> 1;                 // 0..3: 32-row band (m)
  const int wc = wv & 1;                  // 0..1: 64-col half (o)
  const int bm0 = blockIdx.x << 7;        // flattened [B*N] row base
  const int b = bm0 >> 13;
  const int m0 = bm0 & (N_ - 1);

  // ---- B staging: global_load_lds from wt, pre-swizzled source ----
  const int brow = tid >> 3;                    // o row 0..63 (call 0), +64
  const int blc = (tid & 7) ^ (brow & 7);
  const bf16* gb0 = wt + (size_t)brow * F_ + (blc << 3);
  const bf16* gb1 = wt + (size_t)(brow + 64) * F_ + (blc << 3);
  bf16* lb0 = (bf16*)Bs + tid * 8;
  bf16* lb1 = (bf16*)Bs + (tid + 512) * 8;

  // ---- A staging: fp32 -> bf16 via regs, swizzled ds_write ----
  const int ar = tid >> 2;                      // 0..127
  const int kc = (tid & 3) << 4;                // float offset in row
  const float* gAb = x + (size_t)(bm0 + ar) * F_ + kc;
  const int pc0 = ((tid & 3) << 1) ^ (ar & 7);
  bf16* lA0 = (bf16*)As + ar * 64 + (pc0 << 3);
  bf16* lA1 = (bf16*)As + ar * 64 + ((pc0 ^ 1) << 3);

  // ---- fragment read pointers (swizzle: chunk ^= row&7 == lane&7) ----
  const bf16* pa[2][2];
  const bf16* pb[4][2];
#pragma unroll
  for (int i = 0; i < 2; ++i)
#pragma unroll
    for (int kk = 0; kk < 2; ++kk)
      pa[i][kk] = &As[32 * wr + 16 * i + (lane & 15)]
                     [(((kk << 2) + (lane >> 4)) ^ (lane & 7)) << 3];
#pragma unroll
  for (int j = 0; j < 4; ++j)
#pragma unroll
    for (int kk = 0; kk < 2; ++kk)
      pb[j][kk] = &Bs[64 * wc + 16 * j + (lane & 15)]
                     [(((kk << 2) + (lane >> 4)) ^ (lane & 7)) << 3];

  floatx4 acc[2][4] = {};

  // prefetch A(ks=0)
  float4 pf[4];
#pragma unroll
  for (int q = 0; q < 4; ++q) pf[q] = *(const float4*)(gAb + 4 * q);

#pragma unroll
  for (int ks = 0; ks < 2; ++ks) {
    __syncthreads();
    async_copy16(gb0, lb0);
    async_copy16(gb1, lb1);
    gb0 += 64; gb1 += 64;
    bf16x8 lo, hi;
#pragma unroll
    for (int q = 0; q < 2; ++q) {
      float4 f = pf[q];
      lo[4 * q + 0] = (bf16)f.x; lo[4 * q + 1] = (bf16)f.y;
      lo[4 * q + 2] = (bf16)f.z; lo[4 * q + 3] = (bf16)f.w;
    }
#pragma unroll
    for (int q = 0; q < 2; ++q) {
      float4 f = pf[q + 2];
      hi[4 * q + 0] = (bf16)f.x; hi[4 * q + 1] = (bf16)f.y;
      hi[4 * q + 2] = (bf16)f.z; hi[4 * q + 3] = (bf16)f.w;
    }
    *(bf16x8*)lA0 = lo;
    *(bf16x8*)lA1 = hi;
    __syncthreads();
    // prefetch A(ks+1); wraps on last iter (value unused)
    const float* gn = gAb + (((ks + 1) & 1) << 6);
#pragma unroll
    for (int q = 0; q < 4; ++q) pf[q] = *(const float4*)(gn + 4 * q);

#pragma unroll
    for (int kk = 0; kk < 2; ++kk) {
      bf16x8 av[2], bv[4];
#pragma unroll
      for (int i = 0; i < 2; ++i) av[i] = *(const bf16x8*)pa[i][kk];
#pragma unroll
      for (int j = 0; j < 4; ++j) bv[j] = *(const bf16x8*)pb[j][kk];
#pragma unroll
      for (int i = 0; i < 2; ++i)
#pragma unroll
        for (int j = 0; j < 4; ++j)
          acc[i][j] = __builtin_amdgcn_mfma_f32_16x16x32_bf16(av[i], bv[j],
                                                              acc[i][j], 0, 0, 0);
    }
  }

  // ---- write ut[b][o][m0+row] directly (bf16x4 along 4 consecutive m) ----
  bf16* utb = ut + (size_t)b * F_ * N_;
#pragma unroll
  for (int i = 0; i < 2; ++i)
#pragma unroll
    for (int j = 0; j < 4; ++j) {
      const int o = 64 * wc + 16 * j + (lane & 15);
      const int mrow = m0 + 32 * wr + 16 * i + ((lane >> 4) << 2);
      bf16x4 pk;
#pragma unroll
      for (int r = 0; r < 4; ++r) pk[r] = (bf16)acc[i][j][r];
      *(bf16x4*)(utb + (size_t)o * N_ + mrow) = pk;
    }
}

// ---- K1: v = adj@u; z = v + u + bias; out = z / max(||z||, eps) ----
__global__ __launch_bounds__(512, 4) void k1_graphconv(const float* __restrict__ adj,
                                                       const bf16* __restrict__ ut,
                                                       const float* __restrict__ bias,
                                                       float* __restrict__ out) {
  __shared__ bf16 As[128][64];   // adj tile, bf16, chunk-swizzled
  __shared__ bf16 Bs[128][64];   // ut tile (B^T rows), chunk-swizzled
  __shared__ float ss[2][128];
  const int tid = threadIdx.x;            // 0..511
  const int lane = tid & 63;
  const int wv = tid >> 6;                // 0..7
  const int wr = wv >> 1;                 // 0..3: 32-row band
  const int wc = wv & 1;                  // 0..1: 64-col half
  const int n0 = blockIdx.x << 7;         // 64 n-tiles; XCD = n-tile % 8
  const int b = blockIdx.y;               // 8 b-blocks share adj tile in-XCD
  const bf16* ub = ut + (size_t)b * F_ * N_;

  // ---- B staging: global_load_lds, linear LDS dest, swizzled global src ----
  const int brow = tid >> 3;                    // 0..63 (call 0), +64 (call 1)
  const int blc = (tid & 7) ^ (brow & 7);
  const bf16* gb0 = ub + (size_t)brow * N_ + (blc << 3);
  const bf16* gb1 = ub + (size_t)(brow + 64) * N_ + (blc << 3);
  bf16* lb0 = (bf16*)Bs + tid * 8;
  bf16* lb1 = (bf16*)Bs + (tid + 512) * 8;

  // ---- A staging: fp32 -> bf16 via regs, swizzled ds_write ----
  const int ar = tid >> 2;                      // 0..127
  const int kc = (tid & 3) << 4;                // float offset in row
  const float* gAb = adj + (size_t)(n0 + ar) * N_ + kc;
  const int pc0 = ((tid & 3) << 1) ^ (ar & 7);
  bf16* lA0 = (bf16*)As + ar * 64 + (pc0 << 3);
  bf16* lA1 = (bf16*)As + ar * 64 + ((pc0 ^ 1) << 3);

  // ---- fragment read pointers (swizzle: chunk ^= row&7 == lane&7) ----
  const bf16* pa[2][2];
  const bf16* pb[4][2];
#pragma unroll
  for (int i = 0; i < 2; ++i)
#pragma unroll
    for (int kk = 0; kk < 2; ++kk)
      pa[i][kk] = &As[32 * wr + 16 * i + (lane & 15)]
                     [(((kk << 2) + (lane >> 4)) ^ (lane & 7)) << 3];
#pragma unroll
  for (int j = 0; j < 4; ++j)
#pragma unroll
    for (int kk = 0; kk < 2; ++kk)
      pb[j][kk] = &Bs[64 * wc + 16 * j + (lane & 15)]
                     [(((kk << 2) + (lane >> 4)) ^ (lane & 7)) << 3];

  floatx4 acc[2][4] = {};

  // prefetch A(ks=0)
  float4 pf[4];
#pragma unroll
  for (int q = 0; q < 4; ++q) pf[q] = *(const float4*)(gAb + 4 * q);

  for (int ks = 0; ks < 128; ++ks) {
    __syncthreads();  // compute(ks-1) readers done; pf(ks) arrived
    // B(ks) async copies — only these sit on the pre-compute drain (L2-resident)
    async_copy16(gb0, lb0);
    async_copy16(gb1, lb1);
    gb0 += 64; gb1 += 64;
    // commit A(ks) regs -> bf16 LDS (swizzled)
    bf16x8 lo, hi;
#pragma unroll
    for (int q = 0; q < 2; ++q) {
      float4 f = pf[q];
      lo[4 * q + 0] = (bf16)f.x; lo[4 * q + 1] = (bf16)f.y;
      lo[4 * q + 2] = (bf16)f.z; lo[4 * q + 3] = (bf16)f.w;
    }
#pragma unroll
    for (int q = 0; q < 2; ++q) {
      float4 f = pf[q + 2];
      hi[4 * q + 0] = (bf16)f.x; hi[4 * q + 1] = (bf16)f.y;
      hi[4 * q + 2] = (bf16)f.z; hi[4 * q + 3] = (bf16)f.w;
    }
    *(bf16x8*)lA0 = lo;
    *(bf16x8*)lA1 = hi;
    __syncthreads();  // drains B copies + A ds_writes
    // prefetch A(ks+1) AFTER the barrier: latency hides under the MFMA phase
    const float* gn = gAb + ((size_t)((ks + 1) & 127) << 6);
#pragma unroll
    for (int q = 0; q < 4; ++q) pf[q] = *(const float4*)(gn + 4 * q);

#pragma unroll
    for (int kk = 0; kk < 2; ++kk) {
      bf16x8 av[2], bv[4];
#pragma unroll
      for (int i = 0; i < 2; ++i) av[i] = *(const bf16x8*)pa[i][kk];
#pragma unroll
      for (int j = 0; j < 4; ++j) bv[j] = *(const bf16x8*)pb[j][kk];
#pragma unroll
      for (int i = 0; i < 2; ++i)
#pragma unroll
        for (int j = 0; j < 4; ++j)
          acc[i][j] = __builtin_amdgcn_mfma_f32_16x16x32_bf16(av[i], bv[j],
                                                              acc[i][j], 0, 0, 0);
    }
  }

  // epilogue: z = v + u + bias; rowwise ||z||; out = z/max(||z||,eps)  (fp32)
  float bo[4];
#pragma unroll
  for (int j = 0; j < 4; ++j) bo[j] = bias[64 * wc + 16 * j + (lane & 15)];

  float s[2][4];
#pragma unroll
  for (int i = 0; i < 2; ++i)
#pragma unroll
    for (int r = 0; r < 4; ++r) s[i][r] = 0.0f;
#pragma unroll
  for (int i = 0; i < 2; ++i)
#pragma unroll
    for (int j = 0; j < 4; ++j) {
      floatx4 t = acc[i][j];
      const int col = 64 * wc + 16 * j + (lane & 15);
#pragma unroll
      for (int r = 0; r < 4; ++r) {
        const int rowloc = 32 * wr + 16 * i + ((lane >> 4) << 2) + r;
        // self-add from ut (u never materialized in natural layout)
        t[r] += bo[j] + (float)ub[(size_t)col * N_ + n0 + rowloc];
        s[i][r] += t[r] * t[r];
      }
      acc[i][j] = t;
    }
  // sum across the 16 column-lanes (C layout: col = lane&15)
#pragma unroll
  for (int m = 1; m < 16; m <<= 1)
#pragma unroll
    for (int i = 0; i < 2; ++i)
#pragma unroll
      for (int r = 0; r < 4; ++r) s[i][r] += __shfl_xor(s[i][r], m, 16);

  if ((lane & 15) == 0) {
#pragma unroll
    for (int i = 0; i < 2; ++i)
#pragma unroll
      for (int r = 0; r < 4; ++r)
        ss[wc][32 * wr + 16 * i + ((lane >> 4) << 2) + r] = s[i][r];
  }
  __syncthreads();

  const size_t outbase = ((size_t)b * N_ + n0) * F_;
#pragma unroll
  for (int i = 0; i < 2; ++i)
#pragma unroll
    for (int r = 0; r < 4; ++r) {
      int rowloc = 32 * wr + 16 * i + ((lane >> 4) << 2) + r;
      float tot = ss[0][rowloc] + ss[1][rowloc];
      float inv = 1.0f / fmaxf(sqrtf(tot), 1e-12f);
      size_t ro = outbase + (size_t)rowloc * F_ + 64 * wc + (lane & 15);
#pragma unroll
      for (int j = 0; j < 4; ++j)
        out[ro + 16 * j] = acc[i][j][r] * inv;
    }
}

extern "C" void kernel_launch(void* const* d_in, const int* in_sizes, int n_in,
                              void* d_out, int out_size, void* d_ws, size_t ws_size,
                              hipStream_t stream) {
  (void)in_sizes; (void)n_in; (void)out_size; (void)ws_size;
  const float* x    = (const float*)d_in[0];  // [8][8192][128] fp32
  const float* adj  = (const float*)d_in[1];  // [8192][8192]   fp32
  const float* w    = (const float*)d_in[2];  // [128][128]     fp32
  const float* bias = (const float*)d_in[3];  // [128]          fp32
  float* out = (float*)d_out;                 // [8][8192][128] fp32
  bf16* ut = (bf16*)d_ws;                     // ut[8][128][8192] bf16, 16 MB
  bf16* wt = ut + (size_t)B_ * F_ * N_;       // wt[128][128]     bf16, 32 KB

  k0w<<<dim3(1), dim3(256), 0, stream>>>(w, wt);
  k0_xw_t<<<dim3(512), dim3(512), 0, stream>>>(x, wt, ut);
  k1_graphconv<<<dim3(64, 8), dim3(512), 0, stream>>>(adj, ut, bias, out);
}